// Round 1
// baseline (102.348 us; speedup 1.0000x reference)
//
#include <hip/hip_runtime.h>

#define IMG_H 1024
#define IMG_W 1024
#define IMG_C 3

__global__ __launch_bounds__(256) void median5_kernel(const float* __restrict__ img,
                                                      float* __restrict__ out) {
    int idx = blockIdx.x * blockDim.x + threadIdx.x;
    const int total = IMG_C * IMG_H * IMG_W;
    if (idx >= total) return;

    int x = idx % IMG_W;
    int t = idx / IMG_W;
    int y = t % IMG_H;
    int c = t / IMG_H;

    const float* p = img + (size_t)c * IMG_H * IMG_W;
    const float INF = __builtin_inff();

    float v[32];
#pragma unroll
    for (int i = 25; i < 32; ++i) v[i] = INF;

#pragma unroll
    for (int dy = -2; dy <= 2; ++dy) {
#pragma unroll
        for (int dx = -2; dx <= 2; ++dx) {
            int yy = y + dy;
            int xx = x + dx;
            bool valid = (yy >= 0) && (yy <= IMG_H - 2) && (xx >= 0) && (xx <= IMG_W - 2);
            int yc = min(max(yy, 0), IMG_H - 1);
            int xc = min(max(xx, 0), IMG_W - 1);
            float val = p[yc * IMG_W + xc];
            v[(dy + 2) * 5 + (dx + 2)] = valid ? val : INF;
        }
    }

    // Fully-unrolled bitonic sort of 32 elements (ascending).
#pragma unroll
    for (int k = 2; k <= 32; k <<= 1) {
#pragma unroll
        for (int j = k >> 1; j > 0; j >>= 1) {
#pragma unroll
            for (int i = 0; i < 32; ++i) {
                int l = i ^ j;
                if (l > i) {
                    bool up = ((i & k) == 0);
                    float a = v[i];
                    float b = v[l];
                    float mn = fminf(a, b);
                    float mx = fmaxf(a, b);
                    v[i] = up ? mn : mx;
                    v[l] = up ? mx : mn;
                }
            }
        }
    }

    // Count of valid window elements: valid yy range is [max(y-2,0), min(y+2,H-2)].
    int ny = min(y + 2, IMG_H - 2) - max(y - 2, 0) + 1;
    int nx = min(x + 2, IMG_W - 2) - max(x - 2, 0) + 1;
    int n = ny * nx;
    int ilo = (n - 1) >> 1;  // <= 12
    int ihi = n >> 1;        // <= 12

    float lo = 0.0f, hi = 0.0f;
#pragma unroll
    for (int i = 0; i < 13; ++i) {
        if (i == ilo) lo = v[i];
        if (i == ihi) hi = v[i];
    }

    out[idx] = 0.5f * (lo + hi);
}

extern "C" void kernel_launch(void* const* d_in, const int* in_sizes, int n_in,
                              void* d_out, int out_size, void* d_ws, size_t ws_size,
                              hipStream_t stream) {
    const float* img = (const float*)d_in[0];
    float* out = (float*)d_out;
    const int total = IMG_C * IMG_H * IMG_W;
    dim3 block(256);
    dim3 grid((total + 255) / 256);
    median5_kernel<<<grid, block, 0, stream>>>(img, out);
}

// Round 2
// 96.411 us; speedup vs baseline: 1.0616x; 1.0616x over previous
//
#include <hip/hip_runtime.h>

#define IMG_H 1024
#define IMG_W 1024
#define IMG_C 3

__device__ __forceinline__ void CE(float& a, float& b) {
    float t = fminf(a, b);
    b = fmaxf(a, b);
    a = t;
}

// Bubble/insertion sort of 5 — trivially correct (4+3+2+1 CEs).
__device__ __forceinline__ void sort5(float* a) {
    CE(a[0], a[1]); CE(a[1], a[2]); CE(a[2], a[3]); CE(a[3], a[4]);
    CE(a[0], a[1]); CE(a[1], a[2]); CE(a[2], a[3]);
    CE(a[0], a[1]); CE(a[1], a[2]);
    CE(a[0], a[1]);
}

// Batcher odd-even merges (0-indexed, evens-with-evens). Verified by 0-1 principle.
__device__ __forceinline__ void merge22(const float* A, const float* B, float* out) {
    float e0 = fminf(A[0], B[0]), e1 = fmaxf(A[0], B[0]);
    float o0 = fminf(A[1], B[1]), o1 = fmaxf(A[1], B[1]);
    out[0] = e0;
    out[1] = fminf(o0, e1); out[2] = fmaxf(o0, e1);
    out[3] = o1;
}

__device__ __forceinline__ void merge33(const float* A, const float* B, float* out) {
    float Ae[2] = {A[0], A[2]}, Be[2] = {B[0], B[2]};
    float E[4];
    merge22(Ae, Be, E);
    float O0 = fminf(A[1], B[1]), O1 = fmaxf(A[1], B[1]);
    out[0] = E[0];
    out[1] = fminf(O0, E[1]); out[2] = fmaxf(O0, E[1]);
    out[3] = fminf(O1, E[2]); out[4] = fmaxf(O1, E[2]);
    out[5] = E[3];
}

__device__ __forceinline__ void merge55(const float* A, const float* B, float* out) {
    float Ae[3] = {A[0], A[2], A[4]}, Be[3] = {B[0], B[2], B[4]};
    float E[6];
    merge33(Ae, Be, E);
    float Ao[2] = {A[1], A[3]}, Bo[2] = {B[1], B[3]};
    float O[4];
    merge22(Ao, Bo, O);
    out[0] = E[0];
    out[1] = fminf(O[0], E[1]); out[2] = fmaxf(O[0], E[1]);
    out[3] = fminf(O[1], E[2]); out[4] = fmaxf(O[1], E[2]);
    out[5] = fminf(O[2], E[3]); out[6] = fmaxf(O[2], E[3]);
    out[7] = fminf(O[3], E[4]); out[8] = fmaxf(O[3], E[4]);
    out[9] = E[5];
}

__device__ __forceinline__ void merge1010(const float* A, const float* B, float* out) {
    float Ae[5] = {A[0], A[2], A[4], A[6], A[8]}, Be[5] = {B[0], B[2], B[4], B[6], B[8]};
    float E[10];
    merge55(Ae, Be, E);
    float Ao[5] = {A[1], A[3], A[5], A[7], A[9]}, Bo[5] = {B[1], B[3], B[5], B[7], B[9]};
    float O[10];
    merge55(Ao, Bo, O);
    out[0] = E[0];
#pragma unroll
    for (int i = 0; i < 9; ++i) {
        out[2 * i + 1] = fminf(O[i], E[i + 1]);
        out[2 * i + 2] = fmaxf(O[i], E[i + 1]);
    }
    out[19] = O[9];
}

__global__ __launch_bounds__(256) void median5_kernel(const float* __restrict__ img,
                                                      float* __restrict__ out) {
    int idx = blockIdx.x * blockDim.x + threadIdx.x;
    const int total = IMG_C * IMG_H * IMG_W;
    if (idx >= total) return;

    int x = idx % IMG_W;
    int t = idx / IMG_W;
    int y = t % IMG_H;
    int c = t / IMG_H;

    const float* p = img + (size_t)c * IMG_H * IMG_W;
    const float INF = __builtin_inff();

    // Interior: whole 5x5 window valid (valid = coord in [0, 1022]).
    bool interior = (y >= 2) && (y <= IMG_H - 4) && (x >= 2) && (x <= IMG_W - 4);

    float result;
    if (interior) {
        // --- fast path: exact median of 25 via column sorts + Batcher merges ---
        float col[5][5];
#pragma unroll
        for (int j = 0; j < 5; ++j) {
#pragma unroll
            for (int r = 0; r < 5; ++r) {
                col[j][r] = p[(y - 2 + r) * IMG_W + (x - 2 + j)];
            }
            sort5(col[j]);
        }
        float m1[10], m2[10];
        merge55(col[0], col[1], m1);
        merge55(col[2], col[3], m2);
        float m[20];
        merge1010(m1, m2, m);  // sorted 20; unused outputs are DCE'd

        // median(25) = rank-5 (0-indexed) of {m[7..12]} ∪ {col4} (proof: the 7
        // excluded lows m[0..6] are always <= answer, the 7 excluded highs
        // m[13..19] always >= answer).
        float A[6] = {m[7], m[8], m[9], m[10], m[11], m[12]};
        float B[6] = {col[4][0], col[4][1], col[4][2], col[4][3], col[4][4], INF};
        // merge66(A,B) but we only need out[5] = min(O[2], E[3]).
        float Ae[3] = {A[0], A[2], A[4]}, Be3[3] = {B[0], B[2], B[4]};
        float E[6];
        merge33(Ae, Be3, E);
        float Ao[3] = {A[1], A[3], A[5]}, Bo3[3] = {B[1], B[3], B[5]};
        float O[6];
        merge33(Ao, Bo3, O);
        result = fminf(O[2], E[3]);
    } else {
        // --- boundary path: verified bitonic-32 with inf padding ---
        float v[32];
#pragma unroll
        for (int i = 25; i < 32; ++i) v[i] = INF;
#pragma unroll
        for (int dy = -2; dy <= 2; ++dy) {
#pragma unroll
            for (int dx = -2; dx <= 2; ++dx) {
                int yy = y + dy;
                int xx = x + dx;
                bool valid = (yy >= 0) && (yy <= IMG_H - 2) && (xx >= 0) && (xx <= IMG_W - 2);
                int yc = min(max(yy, 0), IMG_H - 1);
                int xc = min(max(xx, 0), IMG_W - 1);
                float val = p[yc * IMG_W + xc];
                v[(dy + 2) * 5 + (dx + 2)] = valid ? val : INF;
            }
        }
#pragma unroll
        for (int k = 2; k <= 32; k <<= 1) {
#pragma unroll
            for (int j = k >> 1; j > 0; j >>= 1) {
#pragma unroll
                for (int i = 0; i < 32; ++i) {
                    int l = i ^ j;
                    if (l > i) {
                        bool up = ((i & k) == 0);
                        float a = v[i];
                        float b = v[l];
                        float mn = fminf(a, b);
                        float mx = fmaxf(a, b);
                        v[i] = up ? mn : mx;
                        v[l] = up ? mx : mn;
                    }
                }
            }
        }
        int ny = min(y + 2, IMG_H - 2) - max(y - 2, 0) + 1;
        int nx = min(x + 2, IMG_W - 2) - max(x - 2, 0) + 1;
        int n = ny * nx;
        int ilo = (n - 1) >> 1;
        int ihi = n >> 1;
        float lo = 0.0f, hi = 0.0f;
#pragma unroll
        for (int i = 0; i < 13; ++i) {
            if (i == ilo) lo = v[i];
            if (i == ihi) hi = v[i];
        }
        result = 0.5f * (lo + hi);
    }

    out[idx] = result;
}

extern "C" void kernel_launch(void* const* d_in, const int* in_sizes, int n_in,
                              void* d_out, int out_size, void* d_ws, size_t ws_size,
                              hipStream_t stream) {
    const float* img = (const float*)d_in[0];
    float* out = (float*)d_out;
    const int total = IMG_C * IMG_H * IMG_W;
    dim3 block(256);
    dim3 grid((total + 255) / 256);
    median5_kernel<<<grid, block, 0, stream>>>(img, out);
}

// Round 3
// 75.529 us; speedup vs baseline: 1.3551x; 1.2765x over previous
//
#include <hip/hip_runtime.h>

#define IMG_H 1024
#define IMG_W 1024
#define IMG_C 3

// Interior strip geometry: each interior thread computes 4 pixels in a row.
// Interior pixel region: y in [2,1020], x in [2,1020]  (window coords all <= 1022)
#define STRIPS_PER_ROW 255                       // x0 = 2 + 4*s, s in [0,255)
#define INT_ROWS 1019                            // y = 2..1020
#define N_STRIPS (IMG_C * INT_ROWS * STRIPS_PER_ROW)   // 779,535
#define NB_INT ((N_STRIPS + 255) / 256)          // 3046
#define BND_PER_C 10215                          // 5*1024 full rows + 1019*5 side cols
#define N_BND (IMG_C * BND_PER_C)                // 30,645
#define NB_BND ((N_BND + 255) / 256)             // 120

__device__ __forceinline__ void CE(float& a, float& b) {
    float t = fminf(a, b);
    b = fmaxf(a, b);
    a = t;
}

__device__ __forceinline__ void sort5(float* a) {
    CE(a[0], a[1]); CE(a[1], a[2]); CE(a[2], a[3]); CE(a[3], a[4]);
    CE(a[0], a[1]); CE(a[1], a[2]); CE(a[2], a[3]);
    CE(a[0], a[1]); CE(a[1], a[2]);
    CE(a[0], a[1]);
}

// Batcher odd-even merges (verified round 2, absmax 0).
__device__ __forceinline__ void merge22(const float* A, const float* B, float* out) {
    float e0 = fminf(A[0], B[0]), e1 = fmaxf(A[0], B[0]);
    float o0 = fminf(A[1], B[1]), o1 = fmaxf(A[1], B[1]);
    out[0] = e0;
    out[1] = fminf(o0, e1); out[2] = fmaxf(o0, e1);
    out[3] = o1;
}

__device__ __forceinline__ void merge33(const float* A, const float* B, float* out) {
    float Ae[2] = {A[0], A[2]}, Be[2] = {B[0], B[2]};
    float E[4];
    merge22(Ae, Be, E);
    float O0 = fminf(A[1], B[1]), O1 = fmaxf(A[1], B[1]);
    out[0] = E[0];
    out[1] = fminf(O0, E[1]); out[2] = fmaxf(O0, E[1]);
    out[3] = fminf(O1, E[2]); out[4] = fmaxf(O1, E[2]);
    out[5] = E[3];
}

__device__ __forceinline__ void merge55(const float* A, const float* B, float* out) {
    float Ae[3] = {A[0], A[2], A[4]}, Be[3] = {B[0], B[2], B[4]};
    float E[6];
    merge33(Ae, Be, E);
    float Ao[2] = {A[1], A[3]}, Bo[2] = {B[1], B[3]};
    float O[4];
    merge22(Ao, Bo, O);
    out[0] = E[0];
    out[1] = fminf(O[0], E[1]); out[2] = fmaxf(O[0], E[1]);
    out[3] = fminf(O[1], E[2]); out[4] = fmaxf(O[1], E[2]);
    out[5] = fminf(O[2], E[3]); out[6] = fmaxf(O[2], E[3]);
    out[7] = fminf(O[3], E[4]); out[8] = fmaxf(O[3], E[4]);
    out[9] = E[5];
}

// merge of two sorted-10s, returning only outputs 7..12 (compiler DCEs the rest).
__device__ __forceinline__ void merge1010_mid(const float* A, const float* B, float* mid) {
    float Ae[5] = {A[0], A[2], A[4], A[6], A[8]}, Be[5] = {B[0], B[2], B[4], B[6], B[8]};
    float E[10];
    merge55(Ae, Be, E);
    float Ao[5] = {A[1], A[3], A[5], A[7], A[9]}, Bo[5] = {B[1], B[3], B[5], B[7], B[9]};
    float O[10];
    merge55(Ao, Bo, O);
    mid[0] = fminf(O[3], E[4]); mid[1] = fmaxf(O[3], E[4]);  // out[7], out[8]
    mid[2] = fminf(O[4], E[5]); mid[3] = fmaxf(O[4], E[5]);  // out[9], out[10]
    mid[4] = fminf(O[5], E[6]); mid[5] = fmaxf(O[5], E[6]);  // out[11], out[12]
}

// median(25) = rank-5 (0-idx) of mid6 (ascending) ∪ sorted col5 (verified round 2).
__device__ __forceinline__ float final_median(const float* mid, const float* c5) {
    const float INF = __builtin_inff();
    float Ae[3] = {mid[0], mid[2], mid[4]}, Be[3] = {c5[0], c5[2], c5[4]};
    float E[6];
    merge33(Ae, Be, E);
    float Ao[3] = {mid[1], mid[3], mid[5]}, Bo[3] = {c5[1], c5[3], INF};
    float O[6];
    merge33(Ao, Bo, O);
    return fminf(O[2], E[3]);
}

__global__ __launch_bounds__(256) void median5_kernel(const float* __restrict__ img,
                                                      float* __restrict__ out) {
    const float INF = __builtin_inff();

    if (blockIdx.x < NB_INT) {
        // ================= interior: 4-pixel strips, shared CE network =========
        int gid = blockIdx.x * 256 + threadIdx.x;
        if (gid >= N_STRIPS) return;
        int xs = gid % STRIPS_PER_ROW;
        int t = gid / STRIPS_PER_ROW;
        int y = 2 + t % INT_ROWS;
        int c = t / INT_ROWS;
        int x0 = 2 + 4 * xs;

        const float* p = img + (size_t)c * IMG_H * IMG_W;
        float* po = out + (size_t)c * IMG_H * IMG_W + (size_t)y * IMG_W;

        // load 8 columns (x0-2 .. x0+5) x 5 rows; x0-2 = 4*xs -> 16B aligned
        float col[8][5];
#pragma unroll
        for (int r = 0; r < 5; ++r) {
            const float4* rp = (const float4*)(p + (y - 2 + r) * IMG_W + (x0 - 2));
            float4 u = rp[0];
            float4 v = rp[1];
            col[0][r] = u.x; col[1][r] = u.y; col[2][r] = u.z; col[3][r] = u.w;
            col[4][r] = v.x; col[5][r] = v.y; col[6][r] = v.z; col[7][r] = v.w;
        }
#pragma unroll
        for (int j = 0; j < 8; ++j) sort5(col[j]);

        // column-pair merges (absolute pairs, shared across the 4 pixels)
        float M0[10], M1[10], M2[10], M3[10];
        merge55(col[0], col[1], M0);
        merge55(col[2], col[3], M1);
        merge55(col[4], col[5], M2);
        merge55(col[6], col[7], M3);

        float mid[6];
        float r0, r1, r2, r3;
        merge1010_mid(M0, M1, mid);
        r0 = final_median(mid, col[4]);          // pixel x0   : cols 0..4, single=col4
        merge1010_mid(M1, M2, mid);
        r1 = final_median(mid, col[1]);          // pixel x0+1 : cols 1..5, single=col1
        r2 = final_median(mid, col[6]);          // pixel x0+2 : cols 2..6, single=col6
        merge1010_mid(M2, M3, mid);
        r3 = final_median(mid, col[3]);          // pixel x0+3 : cols 3..7, single=col3

        po[x0] = r0;
        po[x0 + 1] = r1;
        po[x0 + 2] = r2;
        if (x0 + 3 <= 1020) po[x0 + 3] = r3;     // x=1021 belongs to boundary path
    } else {
        // ================= boundary frame: verified bitonic-32 path ============
        int gid = (blockIdx.x - NB_INT) * 256 + threadIdx.x;
        if (gid >= N_BND) return;
        int c = gid / BND_PER_C;
        int b = gid % BND_PER_C;
        int y, x;
        if (b < 2048) {                 // rows 0,1
            y = b >> 10; x = b & 1023;
        } else if (b < 5120) {          // rows 1021..1023
            int t2 = b - 2048;
            y = 1021 + (t2 >> 10); x = t2 & 1023;
        } else {                        // rows 2..1020, cols {0,1,1021,1022,1023}
            int t2 = b - 5120;
            y = 2 + t2 / 5;
            int m = t2 % 5;
            x = (m < 2) ? m : (1019 + m);
        }

        const float* p = img + (size_t)c * IMG_H * IMG_W;
        float v[32];
#pragma unroll
        for (int i = 25; i < 32; ++i) v[i] = INF;
#pragma unroll
        for (int dy = -2; dy <= 2; ++dy) {
#pragma unroll
            for (int dx = -2; dx <= 2; ++dx) {
                int yy = y + dy;
                int xx = x + dx;
                bool valid = (yy >= 0) && (yy <= IMG_H - 2) && (xx >= 0) && (xx <= IMG_W - 2);
                int yc = min(max(yy, 0), IMG_H - 1);
                int xc = min(max(xx, 0), IMG_W - 1);
                float val = p[yc * IMG_W + xc];
                v[(dy + 2) * 5 + (dx + 2)] = valid ? val : INF;
            }
        }
#pragma unroll
        for (int k = 2; k <= 32; k <<= 1) {
#pragma unroll
            for (int j = k >> 1; j > 0; j >>= 1) {
#pragma unroll
                for (int i = 0; i < 32; ++i) {
                    int l = i ^ j;
                    if (l > i) {
                        bool up = ((i & k) == 0);
                        float a = v[i];
                        float b2 = v[l];
                        float mn = fminf(a, b2);
                        float mx = fmaxf(a, b2);
                        v[i] = up ? mn : mx;
                        v[l] = up ? mx : mn;
                    }
                }
            }
        }
        int ny = min(y + 2, IMG_H - 2) - max(y - 2, 0) + 1;
        int nx = min(x + 2, IMG_W - 2) - max(x - 2, 0) + 1;
        int n = ny * nx;
        int ilo = (n - 1) >> 1;
        int ihi = n >> 1;
        float lo = 0.0f, hi = 0.0f;
#pragma unroll
        for (int i = 0; i < 13; ++i) {
            if (i == ilo) lo = v[i];
            if (i == ihi) hi = v[i];
        }
        out[(size_t)c * IMG_H * IMG_W + (size_t)y * IMG_W + x] = 0.5f * (lo + hi);
    }
}

extern "C" void kernel_launch(void* const* d_in, const int* in_sizes, int n_in,
                              void* d_out, int out_size, void* d_ws, size_t ws_size,
                              hipStream_t stream) {
    const float* img = (const float*)d_in[0];
    float* out = (float*)d_out;
    dim3 block(256);
    dim3 grid(NB_INT + NB_BND);
    median5_kernel<<<grid, block, 0, stream>>>(img, out);
}

// Round 4
// 72.120 us; speedup vs baseline: 1.4191x; 1.0473x over previous
//
#include <hip/hip_runtime.h>

#define IMG_H 1024
#define IMG_W 1024
#define IMG_C 3

// Interior: x in [2,1017], 8 px per thread, 127 full strips per row (no guards).
// x in {1018,1019,1020} plus the frame goes to the boundary path.
#define SPR 127
#define INT_ROWS 1019                          // y = 2..1020
#define N_STRIPS (IMG_C * INT_ROWS * SPR)      // 388,239
#define NB_INT ((N_STRIPS + 255) / 256)        // 1517
#define BND_PER_C (5 * 1024 + INT_ROWS * 8)    // 13,272
#define N_BND (IMG_C * BND_PER_C)              // 39,816
#define NB_BND ((N_BND + 255) / 256)           // 156

__device__ __forceinline__ void CE(float& a, float& b) {
    float t = fminf(a, b);
    b = fmaxf(a, b);
    a = t;
}

__device__ __forceinline__ void sort5(float* a) {
    CE(a[0], a[1]); CE(a[1], a[2]); CE(a[2], a[3]); CE(a[3], a[4]);
    CE(a[0], a[1]); CE(a[1], a[2]); CE(a[2], a[3]);
    CE(a[0], a[1]); CE(a[1], a[2]);
    CE(a[0], a[1]);
}

// Batcher odd-even merges (verified rounds 2-3, absmax 0).
__device__ __forceinline__ void merge22(const float* A, const float* B, float* out) {
    float e0 = fminf(A[0], B[0]), e1 = fmaxf(A[0], B[0]);
    float o0 = fminf(A[1], B[1]), o1 = fmaxf(A[1], B[1]);
    out[0] = e0;
    out[1] = fminf(o0, e1); out[2] = fmaxf(o0, e1);
    out[3] = o1;
}

__device__ __forceinline__ void merge33(const float* A, const float* B, float* out) {
    float Ae[2] = {A[0], A[2]}, Be[2] = {B[0], B[2]};
    float E[4];
    merge22(Ae, Be, E);
    float O0 = fminf(A[1], B[1]), O1 = fmaxf(A[1], B[1]);
    out[0] = E[0];
    out[1] = fminf(O0, E[1]); out[2] = fmaxf(O0, E[1]);
    out[3] = fminf(O1, E[2]); out[4] = fmaxf(O1, E[2]);
    out[5] = E[3];
}

__device__ __forceinline__ void merge55(const float* A, const float* B, float* out) {
    float Ae[3] = {A[0], A[2], A[4]}, Be[3] = {B[0], B[2], B[4]};
    float E[6];
    merge33(Ae, Be, E);
    float Ao[2] = {A[1], A[3]}, Bo[2] = {B[1], B[3]};
    float O[4];
    merge22(Ao, Bo, O);
    out[0] = E[0];
    out[1] = fminf(O[0], E[1]); out[2] = fmaxf(O[0], E[1]);
    out[3] = fminf(O[1], E[2]); out[4] = fmaxf(O[1], E[2]);
    out[5] = fminf(O[2], E[3]); out[6] = fmaxf(O[2], E[3]);
    out[7] = fminf(O[3], E[4]); out[8] = fmaxf(O[3], E[4]);
    out[9] = E[5];
}

// merge of two sorted-10s, only outputs 7..12 (rest DCE'd).
__device__ __forceinline__ void merge1010_mid(const float* A, const float* B, float* mid) {
    float Ae[5] = {A[0], A[2], A[4], A[6], A[8]}, Be[5] = {B[0], B[2], B[4], B[6], B[8]};
    float E[10];
    merge55(Ae, Be, E);
    float Ao[5] = {A[1], A[3], A[5], A[7], A[9]}, Bo[5] = {B[1], B[3], B[5], B[7], B[9]};
    float O[10];
    merge55(Ao, Bo, O);
    mid[0] = fminf(O[3], E[4]); mid[1] = fmaxf(O[3], E[4]);
    mid[2] = fminf(O[4], E[5]); mid[3] = fmaxf(O[4], E[5]);
    mid[4] = fminf(O[5], E[6]); mid[5] = fmaxf(O[5], E[6]);
}

// median(25) = rank-5 (0-idx) of mid6 (sorted) ∪ sorted col5 (verified rounds 2-3).
__device__ __forceinline__ float final_median(const float* mid, const float* c5) {
    const float INF = __builtin_inff();
    float Ae[3] = {mid[0], mid[2], mid[4]}, Be[3] = {c5[0], c5[2], c5[4]};
    float E[6];
    merge33(Ae, Be, E);
    float Ao[3] = {mid[1], mid[3], mid[5]}, Bo[3] = {c5[1], c5[3], INF};
    float O[6];
    merge33(Ao, Bo, O);
    return fminf(O[2], E[3]);
}

__global__ __launch_bounds__(256) void median5_kernel(const float* __restrict__ img,
                                                      float* __restrict__ out) {
    const float INF = __builtin_inff();

    if (blockIdx.x < NB_INT) {
        // ============ interior: 8-pixel strips, shared CE network ============
        int gid = blockIdx.x * 256 + threadIdx.x;
        if (gid >= N_STRIPS) return;
        int xs = gid % SPR;
        int t = gid / SPR;
        int y = 2 + t % INT_ROWS;
        int c = t / INT_ROWS;
        int x0 = 2 + 8 * xs;

        const float* p = img + (size_t)c * IMG_H * IMG_W;

        // 12 columns (abs x0-2 .. x0+9) x 5 rows; x0-2 = 8*xs -> 32B aligned
        float col[12][5];
#pragma unroll
        for (int r = 0; r < 5; ++r) {
            const float4* rp = (const float4*)(p + (y - 2 + r) * IMG_W + (x0 - 2));
            float4 a = rp[0];
            float4 b = rp[1];
            float4 d = rp[2];
            col[0][r] = a.x; col[1][r] = a.y; col[2][r]  = a.z; col[3][r]  = a.w;
            col[4][r] = b.x; col[5][r] = b.y; col[6][r]  = b.z; col[7][r]  = b.w;
            col[8][r] = d.x; col[9][r] = d.y; col[10][r] = d.z; col[11][r] = d.w;
        }
#pragma unroll
        for (int j = 0; j < 12; ++j) sort5(col[j]);

        // even-aligned column-pair merges, shared across the 8 pixels
        float M0[10], M1[10], M2[10], M3[10], M4[10], M5[10];
        merge55(col[0], col[1], M0);
        merge55(col[2], col[3], M1);
        merge55(col[4], col[5], M2);
        merge55(col[6], col[7], M3);
        merge55(col[8], col[9], M4);
        merge55(col[10], col[11], M5);

        // pixel x0+i uses rel cols i..i+4: two even pairs + one single column
        float mid[6];
        float r0, r1, r2, r3, r4, r5, r6, r7;
        merge1010_mid(M0, M1, mid);
        r0 = final_median(mid, col[4]);
        merge1010_mid(M1, M2, mid);
        r1 = final_median(mid, col[1]);
        r2 = final_median(mid, col[6]);
        merge1010_mid(M2, M3, mid);
        r3 = final_median(mid, col[3]);
        r4 = final_median(mid, col[8]);
        merge1010_mid(M3, M4, mid);
        r5 = final_median(mid, col[5]);
        r6 = final_median(mid, col[10]);
        merge1010_mid(M4, M5, mid);
        r7 = final_median(mid, col[7]);

        float* po = out + (size_t)c * IMG_H * IMG_W + (size_t)y * IMG_W + x0;
        float2* po2 = (float2*)po;               // x0*4 bytes = 8+32*xs -> 8B aligned
        po2[0] = make_float2(r0, r1);
        po2[1] = make_float2(r2, r3);
        po2[2] = make_float2(r4, r5);
        po2[3] = make_float2(r6, r7);
    } else {
        // ============ boundary frame: verified bitonic-32 path ============
        int gid = (blockIdx.x - NB_INT) * 256 + threadIdx.x;
        if (gid >= N_BND) return;
        int c = gid / BND_PER_C;
        int b = gid % BND_PER_C;
        int y, x;
        if (b < 2048) {                 // rows 0,1
            y = b >> 10; x = b & 1023;
        } else if (b < 5120) {          // rows 1021..1023
            int t2 = b - 2048;
            y = 1021 + (t2 >> 10); x = t2 & 1023;
        } else {                        // rows 2..1020, cols {0,1} ∪ {1018..1023}
            int t2 = b - 5120;
            y = 2 + (t2 >> 3);
            int m = t2 & 7;
            x = (m < 2) ? m : (1016 + m);
        }

        const float* p = img + (size_t)c * IMG_H * IMG_W;
        float v[32];
#pragma unroll
        for (int i = 25; i < 32; ++i) v[i] = INF;
#pragma unroll
        for (int dy = -2; dy <= 2; ++dy) {
#pragma unroll
            for (int dx = -2; dx <= 2; ++dx) {
                int yy = y + dy;
                int xx = x + dx;
                bool valid = (yy >= 0) && (yy <= IMG_H - 2) && (xx >= 0) && (xx <= IMG_W - 2);
                int yc = min(max(yy, 0), IMG_H - 1);
                int xc = min(max(xx, 0), IMG_W - 1);
                float val = p[yc * IMG_W + xc];
                v[(dy + 2) * 5 + (dx + 2)] = valid ? val : INF;
            }
        }
#pragma unroll
        for (int k = 2; k <= 32; k <<= 1) {
#pragma unroll
            for (int j = k >> 1; j > 0; j >>= 1) {
#pragma unroll
                for (int i = 0; i < 32; ++i) {
                    int l = i ^ j;
                    if (l > i) {
                        bool up = ((i & k) == 0);
                        float a = v[i];
                        float b2 = v[l];
                        float mn = fminf(a, b2);
                        float mx = fmaxf(a, b2);
                        v[i] = up ? mn : mx;
                        v[l] = up ? mx : mn;
                    }
                }
            }
        }
        int ny = min(y + 2, IMG_H - 2) - max(y - 2, 0) + 1;
        int nx = min(x + 2, IMG_W - 2) - max(x - 2, 0) + 1;
        int n = ny * nx;
        int ilo = (n - 1) >> 1;
        int ihi = n >> 1;
        float lo = 0.0f, hi = 0.0f;
#pragma unroll
        for (int i = 0; i < 13; ++i) {
            if (i == ilo) lo = v[i];
            if (i == ihi) hi = v[i];
        }
        out[(size_t)c * IMG_H * IMG_W + (size_t)y * IMG_W + x] = 0.5f * (lo + hi);
    }
}

extern "C" void kernel_launch(void* const* d_in, const int* in_sizes, int n_in,
                              void* d_out, int out_size, void* d_ws, size_t ws_size,
                              hipStream_t stream) {
    const float* img = (const float*)d_in[0];
    float* out = (float*)d_out;
    dim3 block(256);
    dim3 grid(NB_INT + NB_BND);
    median5_kernel<<<grid, block, 0, stream>>>(img, out);
}